// Round 9
// baseline (241.553 us; speedup 1.0000x reference)
//
#include <hip/hip_runtime.h>
#include <cstdint>
#include <cstddef>

typedef unsigned short u16;
typedef unsigned int   u32;
typedef unsigned long long u64;
typedef __attribute__((ext_vector_type(8))) short short8;   // 8 bf16 = 4 VGPR
typedef __attribute__((ext_vector_type(4))) float f32x4;

#define M_ROWS 16384
#define N_COLS 256
#define IN_F   1024
#define K_SPL  8192   // 1024 features * 8 basis
#define K_TOT  9216   // + 1024 base (silu) features
// BK=64 chunks: 144 total (128 spline chunks of 8 features, 16 base chunks of 64 feats)
#define NCHUNK 144
#define SPLITK 2
#define CPB    (NCHUNK / SPLITK)   // 72 chunks per block

// ---------- helpers ----------
__device__ __forceinline__ u32 f2bf1(float f) {          // f32 -> bf16 bits, RNE
  u32 u = __float_as_uint(f);
  u += 0x7fffu + ((u >> 16) & 1u);
  return u >> 16;
}
__device__ __forceinline__ u32 pk2(float a, float b) {
  return f2bf1(a) | (f2bf1(b) << 16);
}
__device__ __forceinline__ float silu(float v) {
  return v * __builtin_amdgcn_rcpf(1.f + __expf(-v));
}

// 8 bf16 cubic B-spline basis values for one x, packed as uint4 (16B).
__device__ __forceinline__ uint4 basis8(float xv) {
  float u = fmaf(xv, 2.5f, 5.5f);
  int i0 = (int)u;
  float fr = u - (float)i0;
  float fr2 = fr * fr, fr3 = fr2 * fr;
  float om  = 1.f - fr;
  float om3 = om * om * om;
  float w0 = om3 * (1.f / 6.f);
  float w3 = fr3 * (1.f / 6.f);
  float w1 = fmaf(fr3, 0.5f, fmaf(fr2, -1.f, 2.f / 3.f));
  float w2 = fmaf(fr + fr2 - fr3, 0.5f, 1.f / 6.f);
  u64 W = (u64)pk2(w0, w1) | ((u64)pk2(w2, w3) << 32);
  if (!(u >= 0.f && u < 11.f)) W = 0ull;
  int s = (i0 - 3) * 16;
  u64 lo, hi;
  if (s >= 64)      { int r = s - 64; lo = 0ull; hi = (r < 64) ? (W << r) : 0ull; }
  else if (s > 0)   { lo = W << s;    hi = W >> (64 - s); }
  else if (s == 0)  { lo = W;         hi = 0ull; }
  else              { int r = -s;     lo = (r < 64) ? (W >> r) : 0ull; hi = 0ull; }
  uint4 o;
  o.x = (u32)lo; o.y = (u32)(lo >> 32); o.z = (u32)hi; o.w = (u32)(hi >> 32);
  return o;
}

// ---------- kernel 1: pack [spline_weight | base_weight] -> bf16, (256 x 9216) row-major ----------
__global__ void pack_weights(const float* __restrict__ bw, const float* __restrict__ sw,
                             u16* __restrict__ Bp) {
  int o  = blockIdx.y;
  int k4 = (blockIdx.x * blockDim.x + threadIdx.x) * 4;
  const float* src = (k4 < K_SPL) ? (sw + (size_t)o * K_SPL + k4)
                                  : (bw + (size_t)o * IN_F + (k4 - K_SPL));
  float a = src[0], b = src[1], c = src[2], d = src[3];
  uint2 v; v.x = pk2(a, b); v.y = pk2(c, d);
  *(uint2*)(Bp + (size_t)o * K_TOT + k4) = v;
}

// ---------- kernel 2: fused KAN GEMM (m201-shape port) ----------
// R9 = R8 resubmit (container infra failure, no kernel verdict; audit found
// no hang/OOB path — barriers uniform, addresses in-bounds, vmcnt counts
// match emitted load counts, VGPR ~200 < 256 cap so no spill trap).
// Theory: R7 showed deep pipeline at 4 MFMA/phase regresses (barrier
// overhead); R4's tally says LDS bytes/MFMA is the joint lever. m201
// geometry: BM=128 BN=256 BK=64, split-K=2 -> grid 256 = 1 block/CU,
// 512 thr = 8 waves of 64x64 tiles (2m x 4n). Per chunk/wave: 16
// ds_read_b128, 32 MFMA (0.69 KB LDS per MFMA vs R4's 1.56). LDS 96KB.
// 2 waves/SIMD -> VGPR cap 256: acc[4][4]+frags cannot spill (WRITE must
// stay ~35MB). One raw s_barrier per chunk, counted vmcnt (never 0
// mid-loop while prefetch continues). Builders: 1024 A-items/chunk over
// 512 thr = 2 each. Swizzle identical to R4 (proven). Split-K=2 adjacent
// partners, 2 atomic writers/line (R4-proven benign).
__global__ __launch_bounds__(512, 2)
void kan_gemm(const float* __restrict__ x, const u16* __restrict__ Bp,
              float* __restrict__ out) {
  __shared__ __align__(16) u16 Bs[2 * 256 * 64];   // 64 KB (2 bufs)
  __shared__ __align__(16) u16 As[2 * 128 * 64];   // 32 KB (2 bufs)

  const int tid  = threadIdx.x;
  const int lane = tid & 63;
  const int w    = tid >> 6;          // 0..7
  const int wm   = w & 1;             // m-half (64 rows)
  const int wn   = w >> 1;            // n-quarter (64 cols)

  const int bid  = blockIdx.x;        // 256
  const int kid  = bid & 1;           // adjacent split-K partners
  const int mb   = bid >> 1;          // 0..127
  const int row0 = mb * 128;
  const int cs   = kid * CPB, c1 = cs + CPB;

  f32x4 acc[4][4];
#pragma unroll
  for (int i = 0; i < 4; ++i)
#pragma unroll
    for (int j = 0; j < 4; ++j)
      acc[i][j] = (f32x4){0.f, 0.f, 0.f, 0.f};

  // builders: thread t builds row br = t>>2, slots bq and bq+4 (2 of 8).
  const int br = tid >> 2;            // 0..127
  const int bq = tid & 3;             // slot 0..3 (and +4)
  const int a_wr0 = br * 64 + ((bq ^ (br & 7)) * 8);
  const int a_wr1 = br * 64 + (((bq + 4) ^ (br & 7)) * 8);

  // fragment read offsets (u16 idx within one buffer), R4-proven swizzle.
  // h=1 (k-half) = offset ^ 32 (slot field ^4).
  const int lm = lane & 15;
  const int kg = lane >> 4;
  int a_off[4], b_off[4];
#pragma unroll
  for (int i = 0; i < 4; ++i) {
    int ra = wm * 64 + i * 16 + lm;   // 0..127
    a_off[i] = ra * 64 + ((kg ^ (ra & 7)) * 8);
  }
#pragma unroll
  for (int j = 0; j < 4; ++j) {
    int rb = wn * 64 + j * 16 + lm;   // 0..255
    b_off[j] = rb * 64 + ((kg ^ (rb & 7)) * 8);
  }

  // B staging: 512 thr x 4 iters x 16B = 32 KB chunk; linear LDS dest,
  // inverse-swizzled global source (both-sides-or-neither rule).
  u32 stage_goff[4];
  int stage_loff[4];
#pragma unroll
  for (int it = 0; it < 4; ++it) {
    int s  = tid + it * 512;
    int r_ = s >> 3, cc = (s & 7) ^ (r_ & 7);
    stage_goff[it] = (u32)r_ * K_TOT + cc * 8;
    stage_loff[it] = s * 8;
  }

  float  px0, px1;                 // spline x prefetch (2 slots)
  float4 pb00, pb01, pb10, pb11;   // base x prefetch (2 slots x 8 feats)

  auto LOADX = [&](int c) {        // vm loads: spline 2, base 4
    const float* xr = x + (size_t)(row0 + br) * IN_F;
    if (c < 128) {
      px0 = xr[c * 8 + bq];
      px1 = xr[c * 8 + bq + 4];
    } else {
      const float* xp0 = xr + (c - 128) * 64 + bq * 8;
      const float* xp1 = xr + (c - 128) * 64 + (bq + 4) * 8;
      pb00 = *(const float4*)xp0; pb01 = *(const float4*)(xp0 + 4);
      pb10 = *(const float4*)xp1; pb11 = *(const float4*)(xp1 + 4);
    }
  };

  auto BUILD = [&](int c) {
    u16* Ab = As + (c & 1) * (128 * 64);
    uint4 q0, q1;
    if (c < 128) {
      q0 = basis8(px0);
      q1 = basis8(px1);
    } else {
      q0.x = pk2(silu(pb00.x), silu(pb00.y));
      q0.y = pk2(silu(pb00.z), silu(pb00.w));
      q0.z = pk2(silu(pb01.x), silu(pb01.y));
      q0.w = pk2(silu(pb01.z), silu(pb01.w));
      q1.x = pk2(silu(pb10.x), silu(pb10.y));
      q1.y = pk2(silu(pb10.z), silu(pb10.w));
      q1.z = pk2(silu(pb11.x), silu(pb11.y));
      q1.w = pk2(silu(pb11.z), silu(pb11.w));
    }
    *(uint4*)(Ab + a_wr0) = q0;
    *(uint4*)(Ab + a_wr1) = q1;
  };

  auto STAGEB = [&](int c) {       // 4 glds
    u16* base = Bs + (c & 1) * (256 * 64);
#pragma unroll
    for (int it = 0; it < 4; ++it) {
      const u16* gp = Bp + stage_goff[it] + c * 64;
      __builtin_amdgcn_global_load_lds((const __attribute__((address_space(1))) void*)gp,
                                       (__attribute__((address_space(3))) void*)(base + stage_loff[it]),
                                       16, 0, 0);
    }
  };

  // ---- prologue: chunk cs -> buf0; x(cs+1) prefetch in flight at barrier ----
  LOADX(cs);            // 2 vm (cs is spline for both kids: 0 / 72)
  STAGEB(cs);           // 4 glds
  BUILD(cs);            // compiler waits px (vmcnt(4): the 4 newer glds allowed)
  LOADX(cs + 1);        // 2 vm
  asm volatile("s_waitcnt vmcnt(2) lgkmcnt(0)" ::: "memory");  // glds(cs)+builds done
  __builtin_amdgcn_s_barrier();

  // ---- main loop: 1 raw barrier per chunk, counted vmcnt ----
  for (int c = cs; c < c1; ++c) {
    if (c + 1 < c1) STAGEB(c + 1);          // 4 glds into buf^1 (chunk c-1's reads done at last barrier)

    const u16* Ab = As + (c & 1) * (128 * 64);
    const u16* Bb = Bs + (c & 1) * (256 * 64);
    short8 af[2][4], bf[2][4];
#pragma unroll
    for (int h = 0; h < 2; ++h) {
      const int hx = h * 32;
#pragma unroll
      for (int i = 0; i < 4; ++i) af[h][i] = *(const short8*)(Ab + (a_off[i] ^ hx));
#pragma unroll
      for (int j = 0; j < 4; ++j) bf[h][j] = *(const short8*)(Bb + (b_off[j] ^ hx));
    }

    if (c + 1 < c1) BUILD(c + 1);           // px(c+1) from last iter; writes buf^1
    if (c + 2 < c1) LOADX(c + 2);           // 2 (spline) or 4 (base) vm loads

    __builtin_amdgcn_s_setprio(1);
#pragma unroll
    for (int h = 0; h < 2; ++h)
#pragma unroll
      for (int i = 0; i < 4; ++i)
#pragma unroll
        for (int j = 0; j < 4; ++j)
          acc[i][j] = __builtin_amdgcn_mfma_f32_16x16x32_bf16(af[h][i], bf[h][j], acc[i][j], 0, 0, 0);
    __builtin_amdgcn_s_setprio(0);

    if (c + 1 < c1) {
      // at barrier: outstanding = 4 glds(c+1) + xl(c+2); require glds landed.
      const int nx = (c + 2 < c1) ? ((c + 2 < 128) ? 2 : 4) : 0;
      if (nx == 2)      asm volatile("s_waitcnt vmcnt(2) lgkmcnt(0)" ::: "memory");
      else if (nx == 4) asm volatile("s_waitcnt vmcnt(4) lgkmcnt(0)" ::: "memory");
      else              asm volatile("s_waitcnt vmcnt(0) lgkmcnt(0)" ::: "memory");
      __builtin_amdgcn_s_barrier();
    }
  }

  // ---- epilogue: C/D col=lane&15, row=(lane>>4)*4+reg; split-K=2 -> 2 atomic writers ----
  const int lc = lane & 15;
  const int lr = (lane >> 4) * 4;
#pragma unroll
  for (int i = 0; i < 4; ++i) {
#pragma unroll
    for (int j = 0; j < 4; ++j) {
      int gr = row0 + wm * 64 + i * 16 + lr;
      int gc = wn * 64 + j * 16 + lc;
      float* po = out + (size_t)gr * N_COLS + gc;
#pragma unroll
      for (int r = 0; r < 4; ++r)
        unsafeAtomicAdd(po + (size_t)r * N_COLS, acc[i][j][r]);
    }
  }
}

extern "C" void kernel_launch(void* const* d_in, const int* in_sizes, int n_in,
                              void* d_out, int out_size, void* d_ws, size_t ws_size,
                              hipStream_t stream) {
  const float* x  = (const float*)d_in[0];   // 16384 x 1024
  const float* bw = (const float*)d_in[1];   // 256 x 1024
  const float* sw = (const float*)d_in[2];   // 256 x 8192
  float* out = (float*)d_out;                // 16384 x 256 f32
  u16* Bp = (u16*)d_ws;                      // 256 x 9216 bf16 = 4.5 MB

  hipMemsetAsync(d_out, 0, (size_t)M_ROWS * N_COLS * sizeof(float), stream);

  dim3 pgrid(K_TOT / 4 / 256, N_COLS);       // (9, 256)
  pack_weights<<<pgrid, 256, 0, stream>>>(bw, sw, Bp);

  kan_gemm<<<256, 512, 0, stream>>>(x, Bp, out);
}